// Round 5
// baseline (254.402 us; speedup 1.0000x reference)
//
#include <hip/hip_runtime.h>
#include <cstdint>
#include <cstddef>

#define NEGV  -1.0e9f
// 0.125 * log2(e): attention computed in exp2 units
#define QSCALE 0.18033688011112042f

typedef _Float16 h8 __attribute__((ext_vector_type(8)));
typedef _Float16 h4 __attribute__((ext_vector_type(4)));
typedef float    f4 __attribute__((ext_vector_type(4)));

// ---------------------------------------------------------------------------
// ws layout (f16 elements):
//  Wqt: [3][1536][512]  (W^T)   2359296
//  Wot: [3][512][512]   (W^T)    786432
//  Qh : [3][8][8][512][64] (q*QSCALE)  6291456
//  Kh : [8][8][1536][64]        6291456
//  Vt : [8][8][64][1536] (V^T)  6291456
//  Oh : [3][4096][512]          6291456
// ---------------------------------------------------------------------------

static __device__ inline h8 cvt8(float4 a, float4 b) {
    h8 r = { (_Float16)a.x, (_Float16)a.y, (_Float16)a.z, (_Float16)a.w,
             (_Float16)b.x, (_Float16)b.y, (_Float16)b.z, (_Float16)b.w };
    return r;
}

// ========== merged W transpose+cvt: Wqkv (512x1536) and Wout (512x512) ==========
// flat blocks: [0,768) -> Wq tiles (48 x 16), [768,1024) -> Wo tiles (16 x 16)
__global__ __launch_bounds__(256) void wt_cvt(
    const float* __restrict__ q0, const float* __restrict__ q1, const float* __restrict__ q2,
    const float* __restrict__ o0, const float* __restrict__ o1, const float* __restrict__ o2,
    _Float16* __restrict__ Wqt, _Float16* __restrict__ Wot)
{
    const int mod = blockIdx.z;
    const int flat = blockIdx.x;
    const float* s;
    _Float16* d;
    int C, bx, by;
    if (flat < 768) {
        C = 1536; bx = flat % 48; by = flat / 48;
        s = (mod == 0) ? q0 : ((mod == 1) ? q1 : q2);
        d = Wqt + (size_t)mod * 1536 * 512;
    } else {
        C = 512; bx = (flat - 768) % 16; by = (flat - 768) / 16;
        s = (mod == 0) ? o0 : ((mod == 1) ? o1 : o2);
        d = Wot + (size_t)mod * 512 * 512;
    }
    const int c0 = bx * 32, r0 = by * 32;
    __shared__ float tile[32][33];
    const int tr = threadIdx.x >> 3;
    const int tc = (threadIdx.x & 7) * 4;
    float4 v = *reinterpret_cast<const float4*>(&s[(size_t)(r0 + tr) * C + c0 + tc]);
    tile[tr][tc + 0] = v.x; tile[tr][tc + 1] = v.y; tile[tr][tc + 2] = v.z; tile[tr][tc + 3] = v.w;
    __syncthreads();
    h4 o = { (_Float16)tile[tc + 0][tr], (_Float16)tile[tc + 1][tr],
             (_Float16)tile[tc + 2][tr], (_Float16)tile[tc + 3][tr] };
    *reinterpret_cast<h4*>(&d[(size_t)(c0 + tr) * 512 + r0 + tc]) = o;
}

// ======================= QKV projection (f16 MFMA) =======================
// x(f32)[4096][512] @ Wqt^T -> Qh/Kh/Vt. 128x128 tile, BK=32, reg-prefetch,
// f32->f16 fused into A-staging, LDS-transpose epilogues (coalesced stores).
// grid (32 rows, 12 cols, 3): A-panel sharers (same bx) land on same XCD.
__global__ __launch_bounds__(256) void qkv_gemm_f16(
    const float* __restrict__ x0, const float* __restrict__ x1, const float* __restrict__ x2,
    const _Float16* __restrict__ Wqt,
    _Float16* __restrict__ Qh, _Float16* __restrict__ Kh, _Float16* __restrict__ Vt)
{
    const int mod = blockIdx.z;
    const float* __restrict__ A = (mod == 0) ? x0 : ((mod == 1) ? x1 : x2);
    const _Float16* __restrict__ Bw = Wqt + (size_t)mod * 1536 * 512;

    __shared__ _Float16 smem[2 * 128 * 40];   // 20480 B
    _Float16* As = smem;                 // [m][k] stride 40
    _Float16* Bs = smem + 128 * 40;      // [n][k]

    const int t = threadIdx.x;
    const int brow = blockIdx.x * 128, bcol = blockIdx.y * 128;
    const int w = t >> 6, l = t & 63;
    const int wr = (w >> 1) * 64, wc = (w & 1) * 64;
    const int lr = l & 15, lk = (l >> 4) * 8, lg = l >> 4;

    const int sm0 = t >> 2, skk = (t & 3) * 8, sm1 = sm0 + 64;

    f4 acc[4][4] = {};
    float4 axr[2][2];
    h8 brg[2];

    axr[0][0] = *reinterpret_cast<const float4*>(&A[(size_t)(brow + sm0) * 512 + skk]);
    axr[0][1] = *reinterpret_cast<const float4*>(&A[(size_t)(brow + sm0) * 512 + skk + 4]);
    axr[1][0] = *reinterpret_cast<const float4*>(&A[(size_t)(brow + sm1) * 512 + skk]);
    axr[1][1] = *reinterpret_cast<const float4*>(&A[(size_t)(brow + sm1) * 512 + skk + 4]);
    brg[0] = *reinterpret_cast<const h8*>(&Bw[(size_t)(bcol + sm0) * 512 + skk]);
    brg[1] = *reinterpret_cast<const h8*>(&Bw[(size_t)(bcol + sm1) * 512 + skk]);
    *reinterpret_cast<h8*>(&As[sm0 * 40 + skk]) = cvt8(axr[0][0], axr[0][1]);
    *reinterpret_cast<h8*>(&As[sm1 * 40 + skk]) = cvt8(axr[1][0], axr[1][1]);
    *reinterpret_cast<h8*>(&Bs[sm0 * 40 + skk]) = brg[0];
    *reinterpret_cast<h8*>(&Bs[sm1 * 40 + skk]) = brg[1];

    for (int k0 = 0; k0 < 512; k0 += 32) {
        __syncthreads();
        const bool more = (k0 + 32) < 512;
        if (more) {
            const int kn = k0 + 32 + skk;
            axr[0][0] = *reinterpret_cast<const float4*>(&A[(size_t)(brow + sm0) * 512 + kn]);
            axr[0][1] = *reinterpret_cast<const float4*>(&A[(size_t)(brow + sm0) * 512 + kn + 4]);
            axr[1][0] = *reinterpret_cast<const float4*>(&A[(size_t)(brow + sm1) * 512 + kn]);
            axr[1][1] = *reinterpret_cast<const float4*>(&A[(size_t)(brow + sm1) * 512 + kn + 4]);
            brg[0] = *reinterpret_cast<const h8*>(&Bw[(size_t)(bcol + sm0) * 512 + k0 + 32 + skk]);
            brg[1] = *reinterpret_cast<const h8*>(&Bw[(size_t)(bcol + sm1) * 512 + k0 + 32 + skk]);
        }
        h8 af[4], bf[4];
#pragma unroll
        for (int m = 0; m < 4; m++)
            af[m] = *reinterpret_cast<h8*>(&As[(wr + m * 16 + lr) * 40 + lk]);
#pragma unroll
        for (int n = 0; n < 4; n++)
            bf[n] = *reinterpret_cast<h8*>(&Bs[(wc + n * 16 + lr) * 40 + lk]);
        __builtin_amdgcn_s_setprio(1);
#pragma unroll
        for (int m = 0; m < 4; m++)
#pragma unroll
            for (int n = 0; n < 4; n++)
                acc[m][n] = __builtin_amdgcn_mfma_f32_16x16x32_f16(af[m], bf[n], acc[m][n], 0, 0, 0);
        __builtin_amdgcn_s_setprio(0);
        __syncthreads();
        if (more) {
            *reinterpret_cast<h8*>(&As[sm0 * 40 + skk]) = cvt8(axr[0][0], axr[0][1]);
            *reinterpret_cast<h8*>(&As[sm1 * 40 + skk]) = cvt8(axr[1][0], axr[1][1]);
            *reinterpret_cast<h8*>(&Bs[sm0 * 40 + skk]) = brg[0];
            *reinterpret_cast<h8*>(&Bs[sm1 * 40 + skk]) = brg[1];
        }
    }

    const int sec = bcol >> 9;                    // 0=q 1=k 2=v
    const int b = brow >> 9;
    const int nbase = brow & 511;
    const int cbase = bcol - (sec << 9);

    if (sec == 2) {
        // V^T via LDS transpose: smem as Tv[col(cis) 64][key 128+pad]
        _Float16 (*Tv)[136] = reinterpret_cast<_Float16(*)[136]>(smem);
#pragma unroll
        for (int pass = 0; pass < 2; pass++) {
            __syncthreads();
            if ((w & 1) == pass) {                // waves whose wc == pass*64
#pragma unroll
                for (int m = 0; m < 4; m++)
#pragma unroll
                    for (int nn = 0; nn < 4; nn++)
#pragma unroll
                        for (int reg = 0; reg < 4; reg++)
                            Tv[nn * 16 + lr][wr + m * 16 + lg * 4 + reg] =
                                (_Float16)acc[m][nn][reg];
            }
            __syncthreads();
            const int c  = t >> 2;                // 0..63 column within pass
            const int kb = (t & 3) * 32;          // 32-key block
            const int cis = cbase + pass * 64 + c;
            const int hh = cis >> 6, d = cis & 63;
            _Float16* dst = &Vt[(((size_t)b * 8 + hh) * 64 + d) * 1536 + mod * 512 + nbase + kb];
#pragma unroll
            for (int u = 0; u < 4; u++)
                *reinterpret_cast<h8*>(&dst[u * 8]) = *reinterpret_cast<h8*>(&Tv[c][kb + u * 8]);
        }
    } else {
        // Q/K: LDS-transpose -> coalesced h8 row stores (2 passes of 64 rows)
        const float scl = (sec == 0) ? QSCALE : 1.0f;
        _Float16 (*Ts)[136] = reinterpret_cast<_Float16(*)[136]>(smem);
#pragma unroll
        for (int pass = 0; pass < 2; pass++) {
            __syncthreads();
            if ((w >> 1) == pass) {
#pragma unroll
                for (int m = 0; m < 4; m++)
#pragma unroll
                    for (int nn = 0; nn < 4; nn++)
#pragma unroll
                        for (int reg = 0; reg < 4; reg++)
                            Ts[m * 16 + lg * 4 + reg][wc + nn * 16 + lr] =
                                (_Float16)(acc[m][nn][reg] * scl);
            }
            __syncthreads();
#pragma unroll
            for (int it = 0; it < 4; it++) {
                const int idx = t + it * 256;
                const int r = idx >> 4, c = (idx & 15) * 8;
                h8 v = *reinterpret_cast<h8*>(&Ts[r][c]);
                const int n = nbase + pass * 64 + r;
                const int cis = cbase + c;
                const int hh = cis >> 6, d = cis & 63;
                if (sec == 0)
                    *reinterpret_cast<h8*>(&Qh[((((size_t)mod * 8 + b) * 8 + hh) * 512 + n) * 64 + d]) = v;
                else
                    *reinterpret_cast<h8*>(&Kh[(((size_t)b * 8 + hh) * 1536 + mod * 512 + n) * 64 + d]) = v;
            }
        }
    }
}

// ======================= attention (swapped QK^T, lane-local softmax) =======================
// block: 256 thr = 4 waves; QBLK=64 (wave w owns 16 q rows). grid (bh, 8 qtiles, mod):
// bh in blockIdx.x -> K/V sharers (8 qt x 3 mod) all on one XCD; 27.6KB LDS -> 5 blocks/CU.
__global__ __launch_bounds__(256) void attn_f16(
    const _Float16* __restrict__ Qh, const _Float16* __restrict__ Kh, const _Float16* __restrict__ Vt,
    const int* __restrict__ m0, const int* __restrict__ m1, const int* __restrict__ m2,
    _Float16* __restrict__ Oh)
{
    const int mod = blockIdx.z;
    const int bh = blockIdx.x, b = bh >> 3, h = bh & 7;
    const int q0 = blockIdx.y * 64;

    __shared__ _Float16 Ks[64 * 72];    // [key][d]
    __shared__ _Float16 Vs[64 * 72];    // [d][key]
    __shared__ _Float16 Ps[64 * 72];    // [q][key] (wave-local rows)

    const int t = threadIdx.x, w = t >> 6, l = t & 63;
    const int lr = l & 15, lg = l >> 4, lk = lg * 8;

    const _Float16* __restrict__ Qp = Qh + ((((size_t)mod * 8 + b) * 8 + h) * 512 + q0 + w * 16) * 64;
    h8 qf0 = *reinterpret_cast<const h8*>(&Qp[(size_t)lr * 64 + lk]);
    h8 qf1 = *reinterpret_cast<const h8*>(&Qp[(size_t)lr * 64 + 32 + lk]);

    const int* __restrict__ mk = (mod == 0) ? m0 : ((mod == 1) ? m1 : m2);
    const bool msk = mk[b * 512 + q0 + w * 16 + lr] != 0;

    float mrow = -3.0e38f, lsum = 0.f;
    f4 o[4] = {};

    const int sr0 = t >> 3, skk = (t & 7) * 8, sr1 = sr0 + 32;   // 256 thr
    const _Float16* __restrict__ kSrc = Kh + (size_t)bh * 1536 * 64 + skk;
    const _Float16* __restrict__ vSrc = Vt + (size_t)bh * 64 * 1536 + skk;

    h8 krg[2], vrg[2];
    krg[0] = *reinterpret_cast<const h8*>(kSrc + (size_t)sr0 * 64);
    krg[1] = *reinterpret_cast<const h8*>(kSrc + (size_t)sr1 * 64);
    vrg[0] = *reinterpret_cast<const h8*>(vSrc + (size_t)sr0 * 1536);
    vrg[1] = *reinterpret_cast<const h8*>(vSrc + (size_t)sr1 * 1536);
    *reinterpret_cast<h8*>(&Ks[sr0 * 72 + skk]) = krg[0];
    *reinterpret_cast<h8*>(&Ks[sr1 * 72 + skk]) = krg[1];
    *reinterpret_cast<h8*>(&Vs[sr0 * 72 + skk]) = vrg[0];
    *reinterpret_cast<h8*>(&Vs[sr1 * 72 + skk]) = vrg[1];

    for (int c0 = 0; c0 < 1536; c0 += 64) {
        __syncthreads();                       // staged K/V visible
        const bool more = (c0 + 64) < 1536;
        if (more) {                            // issue next-chunk loads early
            const int cn = c0 + 64;
            krg[0] = *reinterpret_cast<const h8*>(kSrc + (size_t)(cn + sr0) * 64);
            krg[1] = *reinterpret_cast<const h8*>(kSrc + (size_t)(cn + sr1) * 64);
            vrg[0] = *reinterpret_cast<const h8*>(vSrc + (size_t)sr0 * 1536 + cn);
            vrg[1] = *reinterpret_cast<const h8*>(vSrc + (size_t)sr1 * 1536 + cn);
        }

        // S^T = K Q^T
        f4 st[4] = {};
        __builtin_amdgcn_s_setprio(1);
#pragma unroll
        for (int kb = 0; kb < 4; kb++) {
            h8 ka0 = *reinterpret_cast<h8*>(&Ks[(kb * 16 + lr) * 72 + lk]);
            h8 ka1 = *reinterpret_cast<h8*>(&Ks[(kb * 16 + lr) * 72 + 32 + lk]);
            st[kb] = __builtin_amdgcn_mfma_f32_16x16x32_f16(ka0, qf0, st[kb], 0, 0, 0);
            st[kb] = __builtin_amdgcn_mfma_f32_16x16x32_f16(ka1, qf1, st[kb], 0, 0, 0);
        }
        __builtin_amdgcn_s_setprio(0);

        if (!msk) {
#pragma unroll
            for (int kb = 0; kb < 4; kb++) { st[kb][0] = NEGV; st[kb][1] = NEGV; st[kb][2] = NEGV; st[kb][3] = NEGV; }
        }
        float cm = fmaxf(fmaxf(fmaxf(st[0][0], st[0][1]), fmaxf(st[0][2], st[0][3])),
                         fmaxf(fmaxf(st[1][0], st[1][1]), fmaxf(st[1][2], st[1][3])));
        cm = fmaxf(cm, fmaxf(fmaxf(fmaxf(st[2][0], st[2][1]), fmaxf(st[2][2], st[2][3])),
                             fmaxf(fmaxf(st[3][0], st[3][1]), fmaxf(st[3][2], st[3][3]))));
        cm = fmaxf(cm, __shfl_xor(cm, 16));
        cm = fmaxf(cm, __shfl_xor(cm, 32));

        if (!__all(cm <= mrow + 8.0f)) {       // defer-max
            const float mn = fmaxf(mrow, cm);
            const float sc = __builtin_amdgcn_exp2f(mrow - mn);
            mrow = mn;
            lsum *= sc;
#pragma unroll
            for (int dg = 0; dg < 4; dg++) o[dg] *= sc;
        }

        float rs = 0.f;
#pragma unroll
        for (int kb = 0; kb < 4; kb++) {
            const float p0 = __builtin_amdgcn_exp2f(st[kb][0] - mrow);
            const float p1 = __builtin_amdgcn_exp2f(st[kb][1] - mrow);
            const float p2 = __builtin_amdgcn_exp2f(st[kb][2] - mrow);
            const float p3 = __builtin_amdgcn_exp2f(st[kb][3] - mrow);
            rs += (p0 + p1) + (p2 + p3);
            h4 ph = { (_Float16)p0, (_Float16)p1, (_Float16)p2, (_Float16)p3 };
            *reinterpret_cast<h4*>(&Ps[(w * 16 + lr) * 72 + kb * 16 + lg * 4]) = ph;
        }
        rs += __shfl_xor(rs, 16);
        rs += __shfl_xor(rs, 32);
        lsum += rs;

        // O^T += V^T P (Ps rows wave-local: in-wave DS order suffices)
        __builtin_amdgcn_s_setprio(1);
#pragma unroll
        for (int kb2 = 0; kb2 < 2; kb2++) {
            h8 pa = *reinterpret_cast<h8*>(&Ps[(w * 16 + lr) * 72 + kb2 * 32 + lk]);
#pragma unroll
            for (int dg = 0; dg < 4; dg++) {
                h8 va = *reinterpret_cast<h8*>(&Vs[(dg * 16 + lr) * 72 + kb2 * 32 + lk]);
                o[dg] = __builtin_amdgcn_mfma_f32_16x16x32_f16(va, pa, o[dg], 0, 0, 0);
            }
        }
        __builtin_amdgcn_s_setprio(0);

        __syncthreads();                       // all K/V reads done
        if (more) {                            // write-late
            *reinterpret_cast<h8*>(&Ks[sr0 * 72 + skk]) = krg[0];
            *reinterpret_cast<h8*>(&Ks[sr1 * 72 + skk]) = krg[1];
            *reinterpret_cast<h8*>(&Vs[sr0 * 72 + skk]) = vrg[0];
            *reinterpret_cast<h8*>(&Vs[sr1 * 72 + skk]) = vrg[1];
        }
    }

    const float inv = 1.f / lsum;
    const size_t row = (size_t)mod * 4096 + b * 512 + q0 + w * 16 + lr;
#pragma unroll
    for (int dg = 0; dg < 4; dg++) {
        h4 ov = { (_Float16)(o[dg][0] * inv), (_Float16)(o[dg][1] * inv),
                  (_Float16)(o[dg][2] * inv), (_Float16)(o[dg][3] * inv) };
        *reinterpret_cast<h4*>(&Oh[row * 512 + h * 64 + dg * 16 + lg * 4]) = ov;
    }
}

// ======================= output projection (f16 MFMA, f32 out) =======================
__global__ __launch_bounds__(256) void out_gemm_f16(
    const _Float16* __restrict__ Oh, const _Float16* __restrict__ Wot,
    float* __restrict__ out)
{
    const int mod = blockIdx.z;
    const _Float16* __restrict__ A  = Oh  + (size_t)mod * 4096 * 512;
    const _Float16* __restrict__ Bw = Wot + (size_t)mod * 512 * 512;
    float* __restrict__ C = out + (size_t)mod * 4096 * 512;

    __shared__ _Float16 smem[2 * 128 * 40];   // 20480 B (also f32[32][132] epilogue)
    _Float16* As = smem;
    _Float16* Bs = smem + 128 * 40;

    const int t = threadIdx.x;
    const int brow = blockIdx.x * 128, bcol = blockIdx.y * 128;
    const int w = t >> 6, l = t & 63;
    const int wr = (w >> 1) * 64, wc = (w & 1) * 64;
    const int lr = l & 15, lk = (l >> 4) * 8, lg = l >> 4;

    const int sm0 = t >> 2, skk = (t & 3) * 8, sm1 = sm0 + 64;

    f4 acc[4][4] = {};
    h8 arg[2], brg[2];

    arg[0] = *reinterpret_cast<const h8*>(&A [(size_t)(brow + sm0) * 512 + skk]);
    arg[1] = *reinterpret_cast<const h8*>(&A [(size_t)(brow + sm1) * 512 + skk]);
    brg[0] = *reinterpret_cast<const h8*>(&Bw[(size_t)(bcol + sm0) * 512 + skk]);
    brg[1] = *reinterpret_cast<const h8*>(&Bw[(size_t)(bcol + sm1) * 512 + skk]);
    *reinterpret_cast<h8*>(&As[sm0 * 40 + skk]) = arg[0];
    *reinterpret_cast<h8*>(&As[sm1 * 40 + skk]) = arg[1];
    *reinterpret_cast<h8*>(&Bs[sm0 * 40 + skk]) = brg[0];
    *reinterpret_cast<h8*>(&Bs[sm1 * 40 + skk]) = brg[1];

    for (int k0 = 0; k0 < 512; k0 += 32) {
        __syncthreads();
        const bool more = (k0 + 32) < 512;
        if (more) {
            const int kn = k0 + 32 + skk;
            arg[0] = *reinterpret_cast<const h8*>(&A [(size_t)(brow + sm0) * 512 + kn]);
            arg[1] = *reinterpret_cast<const h8*>(&A [(size_t)(brow + sm1) * 512 + kn]);
            brg[0] = *reinterpret_cast<const h8*>(&Bw[(size_t)(bcol + sm0) * 512 + kn]);
            brg[1] = *reinterpret_cast<const h8*>(&Bw[(size_t)(bcol + sm1) * 512 + kn]);
        }
        h8 af[4], bf[4];
#pragma unroll
        for (int m = 0; m < 4; m++)
            af[m] = *reinterpret_cast<h8*>(&As[(wr + m * 16 + lr) * 40 + lk]);
#pragma unroll
        for (int n = 0; n < 4; n++)
            bf[n] = *reinterpret_cast<h8*>(&Bs[(wc + n * 16 + lr) * 40 + lk]);
        __builtin_amdgcn_s_setprio(1);
#pragma unroll
        for (int m = 0; m < 4; m++)
#pragma unroll
            for (int n = 0; n < 4; n++)
                acc[m][n] = __builtin_amdgcn_mfma_f32_16x16x32_f16(af[m], bf[n], acc[m][n], 0, 0, 0);
        __builtin_amdgcn_s_setprio(0);
        __syncthreads();
        if (more) {
            *reinterpret_cast<h8*>(&As[sm0 * 40 + skk]) = arg[0];
            *reinterpret_cast<h8*>(&As[sm1 * 40 + skk]) = arg[1];
            *reinterpret_cast<h8*>(&Bs[sm0 * 40 + skk]) = brg[0];
            *reinterpret_cast<h8*>(&Bs[sm1 * 40 + skk]) = brg[1];
        }
    }

    // f32 LDS-transpose epilogue: 4 passes of 32 rows -> float4 coalesced stores
    float (*Tf)[132] = reinterpret_cast<float(*)[132]>(smem);
#pragma unroll
    for (int pass = 0; pass < 4; pass++) {
        __syncthreads();
        if ((w >> 1) == (pass >> 1)) {
#pragma unroll
            for (int mm = 0; mm < 2; mm++) {
                const int m = (pass & 1) * 2 + mm;
#pragma unroll
                for (int nn = 0; nn < 4; nn++)
#pragma unroll
                    for (int reg = 0; reg < 4; reg++)
                        Tf[mm * 16 + lg * 4 + reg][wc + nn * 16 + lr] = acc[m][nn][reg];
            }
        }
        __syncthreads();
        const int r = t >> 3, cb = (t & 7) * 16;
        float* dst = &C[(size_t)(brow + pass * 32 + r) * 512 + bcol + cb];
#pragma unroll
        for (int u = 0; u < 4; u++)
            *reinterpret_cast<float4*>(&dst[u * 4]) = *reinterpret_cast<float4*>(&Tf[r][cb + u * 4]);
    }
}

extern "C" void kernel_launch(void* const* d_in, const int* in_sizes, int n_in,
                              void* d_out, int out_size, void* d_ws, size_t ws_size,
                              hipStream_t stream)
{
    // interleaved inputs: x0,m0,Wqkv0,Wout0, x1,m1,Wqkv1,Wout1, x2,m2,Wqkv2,Wout2
    const float* x0  = (const float*)d_in[0];
    const int*   m0  = (const int*)  d_in[1];
    const float* Wq0 = (const float*)d_in[2];
    const float* Wo0 = (const float*)d_in[3];
    const float* x1  = (const float*)d_in[4];
    const int*   m1  = (const int*)  d_in[5];
    const float* Wq1 = (const float*)d_in[6];
    const float* Wo1 = (const float*)d_in[7];
    const float* x2  = (const float*)d_in[8];
    const int*   m2  = (const int*)  d_in[9];
    const float* Wq2 = (const float*)d_in[10];
    const float* Wo2 = (const float*)d_in[11];

    _Float16* Wqt = (_Float16*)d_ws;       // 2359296
    _Float16* Wot = Wqt + 2359296;         //  786432
    _Float16* Qh  = Wot + 786432;          // 6291456
    _Float16* Kh  = Qh  + 6291456;         // 6291456
    _Float16* Vt  = Kh  + 6291456;         // 6291456
    _Float16* Oh  = Vt  + 6291456;         // 6291456

    wt_cvt<<<dim3(1024, 1, 3), 256, 0, stream>>>(Wq0, Wq1, Wq2, Wo0, Wo1, Wo2, Wqt, Wot);
    qkv_gemm_f16<<<dim3(32, 12, 3), 256, 0, stream>>>(x0, x1, x2, Wqt, Qh, Kh, Vt);
    attn_f16    <<<dim3(64, 8, 3), 256, 0, stream>>>(Qh, Kh, Vt, m0, m1, m2, Oh);
    out_gemm_f16<<<dim3(32, 4, 3), 256, 0, stream>>>(Oh, Wot, (float*)d_out);
}

// Round 6
// 236.290 us; speedup vs baseline: 1.0767x; 1.0767x over previous
//
#include <hip/hip_runtime.h>
#include <cstdint>
#include <cstddef>

#define NEGV  -1.0e9f
// 0.125 * log2(e): attention computed in exp2 units
#define QSCALE 0.18033688011112042f

typedef _Float16 h8 __attribute__((ext_vector_type(8)));
typedef _Float16 h4 __attribute__((ext_vector_type(4)));
typedef float    f4 __attribute__((ext_vector_type(4)));

// ---------------------------------------------------------------------------
// ws layout (f16 elements):
//  Wqt: [3][1536][512]  (W^T)   2359296
//  Wot: [3][512][512]   (W^T)    786432
//  Qh : [3][8][8][512][64] (q*QSCALE)  6291456
//  Kh : [8][8][1536][64]        6291456
//  Vt : [8][8][64][1536] (V^T)  6291456
//  Oh : [3][4096][512]          6291456
// ---------------------------------------------------------------------------

static __device__ inline h8 cvt8(float4 a, float4 b) {
    h8 r = { (_Float16)a.x, (_Float16)a.y, (_Float16)a.z, (_Float16)a.w,
             (_Float16)b.x, (_Float16)b.y, (_Float16)b.z, (_Float16)b.w };
    return r;
}

// ========== merged W transpose+cvt: Wqkv (512x1536) and Wout (512x512) ==========
__global__ __launch_bounds__(256) void wt_cvt(
    const float* __restrict__ q0, const float* __restrict__ q1, const float* __restrict__ q2,
    const float* __restrict__ o0, const float* __restrict__ o1, const float* __restrict__ o2,
    _Float16* __restrict__ Wqt, _Float16* __restrict__ Wot)
{
    const int mod = blockIdx.z;
    const int flat = blockIdx.x;
    const float* s;
    _Float16* d;
    int C, bx, by;
    if (flat < 768) {
        C = 1536; bx = flat % 48; by = flat / 48;
        s = (mod == 0) ? q0 : ((mod == 1) ? q1 : q2);
        d = Wqt + (size_t)mod * 1536 * 512;
    } else {
        C = 512; bx = (flat - 768) % 16; by = (flat - 768) / 16;
        s = (mod == 0) ? o0 : ((mod == 1) ? o1 : o2);
        d = Wot + (size_t)mod * 512 * 512;
    }
    const int c0 = bx * 32, r0 = by * 32;
    __shared__ float tile[32][33];
    const int tr = threadIdx.x >> 3;
    const int tc = (threadIdx.x & 7) * 4;
    float4 v = *reinterpret_cast<const float4*>(&s[(size_t)(r0 + tr) * C + c0 + tc]);
    tile[tr][tc + 0] = v.x; tile[tr][tc + 1] = v.y; tile[tr][tc + 2] = v.z; tile[tr][tc + 3] = v.w;
    __syncthreads();
    h4 o = { (_Float16)tile[tc + 0][tr], (_Float16)tile[tc + 1][tr],
             (_Float16)tile[tc + 2][tr], (_Float16)tile[tc + 3][tr] };
    *reinterpret_cast<h4*>(&d[(size_t)(c0 + tr) * 512 + r0 + tc]) = o;
}

// ======================= QKV projection (f16 MFMA, BK=64) =======================
// x(f32)[4096][512] @ Wqt^T -> Qh/Kh/Vt. 128x128 tile, BK=64 (8 barrier pairs),
// f32->f16 fused into A-staging. grid (32,12,3): A-panel sharers same XCD.
__global__ __launch_bounds__(256) void qkv_gemm_f16(
    const float* __restrict__ x0, const float* __restrict__ x1, const float* __restrict__ x2,
    const _Float16* __restrict__ Wqt,
    _Float16* __restrict__ Qh, _Float16* __restrict__ Kh, _Float16* __restrict__ Vt)
{
    const int mod = blockIdx.z;
    const float* __restrict__ A = (mod == 0) ? x0 : ((mod == 1) ? x1 : x2);
    const _Float16* __restrict__ Bw = Wqt + (size_t)mod * 1536 * 512;

    __shared__ _Float16 smem[2 * 128 * 72];   // 36864 B
    _Float16* As = smem;                 // [m][k] stride 72
    _Float16* Bs = smem + 128 * 72;      // [n][k]

    const int t = threadIdx.x;
    const int brow = blockIdx.x * 128, bcol = blockIdx.y * 128;
    const int w = t >> 6, l = t & 63;
    const int wr = (w >> 1) * 64, wc = (w & 1) * 64;
    const int lr = l & 15, lg = l >> 4, lk = lg * 8;

    // staging: row sm = t>>1 (0..127), k-seg sk = (t&1)*32
    const int sm = t >> 1, sk = (t & 1) * 32;
    const float*    __restrict__ aRow = &A [(size_t)(brow + sm) * 512 + sk];
    const _Float16* __restrict__ bRow = &Bw[(size_t)(bcol + sm) * 512 + sk];
    _Float16* aDst = &As[sm * 72 + sk];
    _Float16* bDst = &Bs[sm * 72 + sk];

    f4 acc[4][4] = {};
    float4 ax[8];
    h8 bx[4];

#pragma unroll
    for (int j = 0; j < 8; j++) ax[j] = *reinterpret_cast<const float4*>(&aRow[j * 4]);
#pragma unroll
    for (int j = 0; j < 4; j++) bx[j] = *reinterpret_cast<const h8*>(&bRow[j * 8]);
#pragma unroll
    for (int j = 0; j < 4; j++) {
        *reinterpret_cast<h8*>(&aDst[j * 8]) = cvt8(ax[2 * j], ax[2 * j + 1]);
        *reinterpret_cast<h8*>(&bDst[j * 8]) = bx[j];
    }

    for (int k0 = 0; k0 < 512; k0 += 64) {
        __syncthreads();
        const bool more = (k0 + 64) < 512;
        if (more) {
            const int kn = k0 + 64;
#pragma unroll
            for (int j = 0; j < 8; j++) ax[j] = *reinterpret_cast<const float4*>(&aRow[kn + j * 4]);
#pragma unroll
            for (int j = 0; j < 4; j++) bx[j] = *reinterpret_cast<const h8*>(&bRow[kn + j * 8]);
        }
#pragma unroll
        for (int ks = 0; ks < 64; ks += 32) {
            h8 af[4], bf[4];
#pragma unroll
            for (int m = 0; m < 4; m++)
                af[m] = *reinterpret_cast<h8*>(&As[(wr + m * 16 + lr) * 72 + ks + lk]);
#pragma unroll
            for (int n = 0; n < 4; n++)
                bf[n] = *reinterpret_cast<h8*>(&Bs[(wc + n * 16 + lr) * 72 + ks + lk]);
            __builtin_amdgcn_s_setprio(1);
#pragma unroll
            for (int m = 0; m < 4; m++)
#pragma unroll
                for (int n = 0; n < 4; n++)
                    acc[m][n] = __builtin_amdgcn_mfma_f32_16x16x32_f16(af[m], bf[n], acc[m][n], 0, 0, 0);
            __builtin_amdgcn_s_setprio(0);
        }
        __syncthreads();
        if (more) {
#pragma unroll
            for (int j = 0; j < 4; j++) {
                *reinterpret_cast<h8*>(&aDst[j * 8]) = cvt8(ax[2 * j], ax[2 * j + 1]);
                *reinterpret_cast<h8*>(&bDst[j * 8]) = bx[j];
            }
        }
    }

    const int sec = bcol >> 9;                    // 0=q 1=k 2=v
    const int b = brow >> 9;
    const int nbase = brow & 511;
    const int cbase = bcol - (sec << 9);

    if (sec == 2) {
        // V^T direct: 4 consecutive keys (reg) per h4 store (R4-style)
#pragma unroll
        for (int m = 0; m < 4; m++) {
            const int n = nbase + wr + m * 16 + lg * 4;
#pragma unroll
            for (int nn = 0; nn < 4; nn++) {
                const int cis = cbase + wc + nn * 16 + lr;
                const int hh = cis >> 6, d = cis & 63;
                h4 pv = { (_Float16)acc[m][nn][0], (_Float16)acc[m][nn][1],
                          (_Float16)acc[m][nn][2], (_Float16)acc[m][nn][3] };
                *reinterpret_cast<h4*>(&Vt[(((size_t)b * 8 + hh) * 64 + d) * 1536 + mod * 512 + n]) = pv;
            }
        }
    } else {
        // Q/K: LDS-transpose -> coalesced h8 row stores (2 passes of 64 rows)
        const float scl = (sec == 0) ? QSCALE : 1.0f;
        _Float16 (*Ts)[136] = reinterpret_cast<_Float16(*)[136]>(smem);
#pragma unroll
        for (int pass = 0; pass < 2; pass++) {
            __syncthreads();
            if ((w >> 1) == pass) {
#pragma unroll
                for (int m = 0; m < 4; m++)
#pragma unroll
                    for (int nn = 0; nn < 4; nn++)
#pragma unroll
                        for (int reg = 0; reg < 4; reg++)
                            Ts[m * 16 + lg * 4 + reg][wc + nn * 16 + lr] =
                                (_Float16)(acc[m][nn][reg] * scl);
            }
            __syncthreads();
#pragma unroll
            for (int it = 0; it < 4; it++) {
                const int idx = t + it * 256;
                const int r = idx >> 4, c = (idx & 15) * 8;
                h8 v = *reinterpret_cast<h8*>(&Ts[r][c]);
                const int n = nbase + pass * 64 + r;
                const int cis = cbase + c;
                const int hh = cis >> 6, d = cis & 63;
                if (sec == 0)
                    *reinterpret_cast<h8*>(&Qh[((((size_t)mod * 8 + b) * 8 + hh) * 512 + n) * 64 + d]) = v;
                else
                    *reinterpret_cast<h8*>(&Kh[(((size_t)b * 8 + hh) * 1536 + mod * 512 + n) * 64 + d]) = v;
            }
        }
    }
}

// ======================= attention (R4 version: QBLK=128, 512 thr) =======================
// grid (bh, qtile, mod): bh in blockIdx.x -> all K/V sharers on one XCD (id%8 = bh%8).
__global__ __launch_bounds__(512) void attn_f16(
    const _Float16* __restrict__ Qh, const _Float16* __restrict__ Kh, const _Float16* __restrict__ Vt,
    const int* __restrict__ m0, const int* __restrict__ m1, const int* __restrict__ m2,
    _Float16* __restrict__ Oh)
{
    const int mod = blockIdx.z;
    const int bh = blockIdx.x, b = bh >> 3, h = bh & 7;
    const int q0 = blockIdx.y * 128;

    __shared__ _Float16 Ks[64 * 72];    // [key][d]
    __shared__ _Float16 Vs[64 * 72];    // [d][key]
    __shared__ _Float16 Ps[128 * 72];   // [q][key] (wave-local rows)

    const int t = threadIdx.x, w = t >> 6, l = t & 63;
    const int lr = l & 15, lg = l >> 4, lk = lg * 8;

    const _Float16* __restrict__ Qp = Qh + ((((size_t)mod * 8 + b) * 8 + h) * 512 + q0 + w * 16) * 64;
    h8 qf0 = *reinterpret_cast<const h8*>(&Qp[(size_t)lr * 64 + lk]);
    h8 qf1 = *reinterpret_cast<const h8*>(&Qp[(size_t)lr * 64 + 32 + lk]);

    const int* __restrict__ mk = (mod == 0) ? m0 : ((mod == 1) ? m1 : m2);
    const bool msk = mk[b * 512 + q0 + w * 16 + lr] != 0;

    float mrow = -3.0e38f, lsum = 0.f;
    f4 o[4] = {};

    const int sr = t >> 3, skk = (t & 7) * 8;       // 512 thr: sr 0..63
    const _Float16* __restrict__ kSrc = Kh + (size_t)bh * 1536 * 64 + (size_t)sr * 64 + skk;
    const _Float16* __restrict__ vSrc = Vt + (size_t)bh * 64 * 1536 + (size_t)sr * 1536 + skk;
    _Float16* kDst = &Ks[sr * 72 + skk];
    _Float16* vDst = &Vs[sr * 72 + skk];

    h8 krg = *reinterpret_cast<const h8*>(kSrc);
    h8 vrg = *reinterpret_cast<const h8*>(vSrc);
    *reinterpret_cast<h8*>(kDst) = krg;
    *reinterpret_cast<h8*>(vDst) = vrg;

    for (int c0 = 0; c0 < 1536; c0 += 64) {
        __syncthreads();                       // staged K/V visible
        const bool more = (c0 + 64) < 1536;
        if (more) {                            // issue next-chunk loads early
            krg = *reinterpret_cast<const h8*>(kSrc + (size_t)(c0 + 64) * 64);
            vrg = *reinterpret_cast<const h8*>(vSrc + (c0 + 64));
        }

        // S^T = K Q^T
        f4 st[4] = {};
        __builtin_amdgcn_s_setprio(1);
#pragma unroll
        for (int kb = 0; kb < 4; kb++) {
            h8 ka0 = *reinterpret_cast<h8*>(&Ks[(kb * 16 + lr) * 72 + lk]);
            h8 ka1 = *reinterpret_cast<h8*>(&Ks[(kb * 16 + lr) * 72 + 32 + lk]);
            st[kb] = __builtin_amdgcn_mfma_f32_16x16x32_f16(ka0, qf0, st[kb], 0, 0, 0);
            st[kb] = __builtin_amdgcn_mfma_f32_16x16x32_f16(ka1, qf1, st[kb], 0, 0, 0);
        }
        __builtin_amdgcn_s_setprio(0);

        if (!msk) {
#pragma unroll
            for (int kb = 0; kb < 4; kb++) { st[kb][0] = NEGV; st[kb][1] = NEGV; st[kb][2] = NEGV; st[kb][3] = NEGV; }
        }
        float cm = fmaxf(fmaxf(fmaxf(st[0][0], st[0][1]), fmaxf(st[0][2], st[0][3])),
                         fmaxf(fmaxf(st[1][0], st[1][1]), fmaxf(st[1][2], st[1][3])));
        cm = fmaxf(cm, fmaxf(fmaxf(fmaxf(st[2][0], st[2][1]), fmaxf(st[2][2], st[2][3])),
                             fmaxf(fmaxf(st[3][0], st[3][1]), fmaxf(st[3][2], st[3][3]))));
        cm = fmaxf(cm, __shfl_xor(cm, 16));
        cm = fmaxf(cm, __shfl_xor(cm, 32));

        if (!__all(cm <= mrow + 8.0f)) {       // defer-max
            const float mn = fmaxf(mrow, cm);
            const float sc = __builtin_amdgcn_exp2f(mrow - mn);
            mrow = mn;
            lsum *= sc;
#pragma unroll
            for (int dg = 0; dg < 4; dg++) o[dg] *= sc;
        }

        float rs = 0.f;
#pragma unroll
        for (int kb = 0; kb < 4; kb++) {
            const float p0 = __builtin_amdgcn_exp2f(st[kb][0] - mrow);
            const float p1 = __builtin_amdgcn_exp2f(st[kb][1] - mrow);
            const float p2 = __builtin_amdgcn_exp2f(st[kb][2] - mrow);
            const float p3 = __builtin_amdgcn_exp2f(st[kb][3] - mrow);
            rs += (p0 + p1) + (p2 + p3);
            h4 ph = { (_Float16)p0, (_Float16)p1, (_Float16)p2, (_Float16)p3 };
            *reinterpret_cast<h4*>(&Ps[(w * 16 + lr) * 72 + kb * 16 + lg * 4]) = ph;
        }
        rs += __shfl_xor(rs, 16);
        rs += __shfl_xor(rs, 32);
        lsum += rs;

        // O^T += V^T P (Ps rows wave-local: in-wave DS order suffices)
        __builtin_amdgcn_s_setprio(1);
#pragma unroll
        for (int kb2 = 0; kb2 < 2; kb2++) {
            h8 pa = *reinterpret_cast<h8*>(&Ps[(w * 16 + lr) * 72 + kb2 * 32 + lk]);
#pragma unroll
            for (int dg = 0; dg < 4; dg++) {
                h8 va = *reinterpret_cast<h8*>(&Vs[(dg * 16 + lr) * 72 + kb2 * 32 + lk]);
                o[dg] = __builtin_amdgcn_mfma_f32_16x16x32_f16(va, pa, o[dg], 0, 0, 0);
            }
        }
        __builtin_amdgcn_s_setprio(0);

        __syncthreads();                       // all K/V reads done
        if (more) {                            // write-late
            *reinterpret_cast<h8*>(kDst) = krg;
            *reinterpret_cast<h8*>(vDst) = vrg;
        }
    }

    const float inv = 1.f / lsum;
    const size_t row = (size_t)mod * 4096 + b * 512 + q0 + w * 16 + lr;
#pragma unroll
    for (int dg = 0; dg < 4; dg++) {
        h4 ov = { (_Float16)(o[dg][0] * inv), (_Float16)(o[dg][1] * inv),
                  (_Float16)(o[dg][2] * inv), (_Float16)(o[dg][3] * inv) };
        *reinterpret_cast<h4*>(&Oh[row * 512 + h * 64 + dg * 16 + lg * 4]) = ov;
    }
}

// ======================= output projection (BM=64, BN=128, BK=64) =======================
// grid (64, 4, 3): 768 blocks = 3/CU; A-panel sharers (same x) same XCD.
__global__ __launch_bounds__(256) void out_gemm_f16(
    const _Float16* __restrict__ Oh, const _Float16* __restrict__ Wot,
    float* __restrict__ out)
{
    const int mod = blockIdx.z;
    const _Float16* __restrict__ A  = Oh  + (size_t)mod * 4096 * 512;
    const _Float16* __restrict__ Bw = Wot + (size_t)mod * 512 * 512;
    float* __restrict__ C = out + (size_t)mod * 4096 * 512;

    __shared__ _Float16 smem[(64 + 128) * 72];   // 27648 B
    _Float16* As = smem;                 // [m 64][k 72]
    _Float16* Bs = smem + 64 * 72;       // [n 128][k 72]

    const int t = threadIdx.x;
    const int brow = blockIdx.x * 64, bcol = blockIdx.y * 128;
    const int w = t >> 6, l = t & 63;
    const int wr = (w >> 1) * 32, wc = (w & 1) * 64;
    const int lr = l & 15, lg = l >> 4, lk = lg * 8;

    // staging: A rows sa = t>>2 (0..63), seg (t&3)*16 (2 h8); B rows sb = t>>1, seg (t&1)*32 (4 h8)
    const int sa = t >> 2, ska = (t & 3) * 16;
    const int sb = t >> 1, skb = (t & 1) * 32;
    const _Float16* __restrict__ aRow = &A [(size_t)(brow + sa) * 512 + ska];
    const _Float16* __restrict__ bRow = &Bw[(size_t)(bcol + sb) * 512 + skb];
    _Float16* aDst = &As[sa * 72 + ska];
    _Float16* bDst = &Bs[sb * 72 + skb];

    f4 acc[2][4] = {};
    h8 axr[2], bxr[4];

#pragma unroll
    for (int j = 0; j < 2; j++) axr[j] = *reinterpret_cast<const h8*>(&aRow[j * 8]);
#pragma unroll
    for (int j = 0; j < 4; j++) bxr[j] = *reinterpret_cast<const h8*>(&bRow[j * 8]);
#pragma unroll
    for (int j = 0; j < 2; j++) *reinterpret_cast<h8*>(&aDst[j * 8]) = axr[j];
#pragma unroll
    for (int j = 0; j < 4; j++) *reinterpret_cast<h8*>(&bDst[j * 8]) = bxr[j];

    for (int k0 = 0; k0 < 512; k0 += 64) {
        __syncthreads();
        const bool more = (k0 + 64) < 512;
        if (more) {
            const int kn = k0 + 64;
#pragma unroll
            for (int j = 0; j < 2; j++) axr[j] = *reinterpret_cast<const h8*>(&aRow[kn + j * 8]);
#pragma unroll
            for (int j = 0; j < 4; j++) bxr[j] = *reinterpret_cast<const h8*>(&bRow[kn + j * 8]);
        }
#pragma unroll
        for (int ks = 0; ks < 64; ks += 32) {
            h8 af[2], bf[4];
#pragma unroll
            for (int m = 0; m < 2; m++)
                af[m] = *reinterpret_cast<h8*>(&As[(wr + m * 16 + lr) * 72 + ks + lk]);
#pragma unroll
            for (int n = 0; n < 4; n++)
                bf[n] = *reinterpret_cast<h8*>(&Bs[(wc + n * 16 + lr) * 72 + ks + lk]);
            __builtin_amdgcn_s_setprio(1);
#pragma unroll
            for (int m = 0; m < 2; m++)
#pragma unroll
                for (int n = 0; n < 4; n++)
                    acc[m][n] = __builtin_amdgcn_mfma_f32_16x16x32_f16(af[m], bf[n], acc[m][n], 0, 0, 0);
            __builtin_amdgcn_s_setprio(0);
        }
        __syncthreads();
        if (more) {
#pragma unroll
            for (int j = 0; j < 2; j++) *reinterpret_cast<h8*>(&aDst[j * 8]) = axr[j];
#pragma unroll
            for (int j = 0; j < 4; j++) *reinterpret_cast<h8*>(&bDst[j * 8]) = bxr[j];
        }
    }

#pragma unroll
    for (int m = 0; m < 2; m++) {
        const int rloc = wr + m * 16 + lg * 4;
#pragma unroll
        for (int reg = 0; reg < 4; reg++) {
            const size_t base = (size_t)(brow + rloc + reg) * 512 + bcol;
#pragma unroll
            for (int nn = 0; nn < 4; nn++)
                C[base + wc + nn * 16 + lr] = acc[m][nn][reg];
        }
    }
}

extern "C" void kernel_launch(void* const* d_in, const int* in_sizes, int n_in,
                              void* d_out, int out_size, void* d_ws, size_t ws_size,
                              hipStream_t stream)
{
    // interleaved inputs: x0,m0,Wqkv0,Wout0, x1,m1,Wqkv1,Wout1, x2,m2,Wqkv2,Wout2
    const float* x0  = (const float*)d_in[0];
    const int*   m0  = (const int*)  d_in[1];
    const float* Wq0 = (const float*)d_in[2];
    const float* Wo0 = (const float*)d_in[3];
    const float* x1  = (const float*)d_in[4];
    const int*   m1  = (const int*)  d_in[5];
    const float* Wq1 = (const float*)d_in[6];
    const float* Wo1 = (const float*)d_in[7];
    const float* x2  = (const float*)d_in[8];
    const int*   m2  = (const int*)  d_in[9];
    const float* Wq2 = (const float*)d_in[10];
    const float* Wo2 = (const float*)d_in[11];

    _Float16* Wqt = (_Float16*)d_ws;       // 2359296
    _Float16* Wot = Wqt + 2359296;         //  786432
    _Float16* Qh  = Wot + 786432;          // 6291456
    _Float16* Kh  = Qh  + 6291456;         // 6291456
    _Float16* Vt  = Kh  + 6291456;         // 6291456
    _Float16* Oh  = Vt  + 6291456;         // 6291456

    wt_cvt<<<dim3(1024, 1, 3), 256, 0, stream>>>(Wq0, Wq1, Wq2, Wo0, Wo1, Wo2, Wqt, Wot);
    qkv_gemm_f16<<<dim3(32, 12, 3), 256, 0, stream>>>(x0, x1, x2, Wqt, Qh, Kh, Vt);
    attn_f16    <<<dim3(64, 4, 3), 512, 0, stream>>>(Qh, Kh, Vt, m0, m1, m2, Oh);
    out_gemm_f16<<<dim3(64, 4, 3), 256, 0, stream>>>(Oh, Wot, (float*)d_out);
}